// Round 1
// baseline (370.398 us; speedup 1.0000x reference)
//
#include <hip/hip_runtime.h>
#include <hip/hip_fp16.h>

// SJLT projection: out[b, idx[d,j]] += x[b,d]*sgn[d,j]; out *= 1/sqrt(8)
// B=32, D=1e6, P=4096, c=8.
//
// R10 post-mortem: occupancy 36->50% but pass_a_transpose stayed 103 us ->
// NOT wave-starved. Chain analysis: rank_and_stage = ballotx7 + LDS atomic
// + shfl broadcast = 2 LDS roundtrips + ~40 VALU per element, serial.
// R11: (a) per-element LDS atomicAdd rank (1 roundtrip, ~8 VALU, ILP across
// int4); (b) fuse pass_b into gather: block per (seg,kb,half) stages by
// low6 into LDS then gathers in-place -> listB 64MB roundtrip + 8M ballot
// chains deleted. Rare bin overflow (cap 96 = +4.5 sigma) handled exactly
// via scaled atomics into pre-zeroed out; reduce accumulates on top.

#define D_TOTAL 1000000
#define PROJ    4096
#define C_SK    8
#define NE      (D_TOTAL * C_SK)     // 8,000,000 entries
#define SCALE   0.35355339059327373f

#define NSEG    16
#define SEG_D   62500                // d per segment (= 4 MB of xT)
#define CAPA2   8448                 // per-(seg,kb) cap (mu=7812, +7.2sig)
#define BINCAP_A 96                  // pass_a per-tile per-bin LDS cap (mu=64,+4sig)
#define CAPH    96                   // gather per-(bucket,half) LDS cap (mu=61,+4.5sig; overflow exact)
#define TILE    4096                 // pass_a tile (512 d)
#define NBLK_A  ((NE + TILE - 1) / TILE)          // 1954
#define NBLK_T  ((D_TOTAL + 255) / 256)           // 3907
#define NSLICE  (NSEG * 2)                        // 32 partial slices

// smem: pass_a stage 64*96*4=24576 + cnt/basek 512 = 25088; transpose tile
// 32*260*2 = 16640 -> union 25088
#define SMEM_FUSED 25088

// ws layout: curA | xT | listA | partial
#define CURA_OFF   0                                   // 1024 ints (16KB pad)
#define XT_OFF     16384
#define XT_SZ      ((size_t)D_TOTAL * 32 * 2)          // 64,000,000
#define LISTA_OFF  (XT_OFF + XT_SZ)                    // 64,016,384
#define LISTA_SZ   ((size_t)NSEG * 64 * CAPA2 * 4)     // 34,603,008
#define PART_OFF   (LISTA_OFF + LISTA_SZ)              // 98,619,392
#define PART_SZ    ((size_t)NSLICE * PROJ * 32 * 4)    // 16,777,216
#define WS_NEED    (PART_OFF + PART_SZ)                // 115,396,608

// ---------------- K0: init cursors ----------------
__global__ void init_cursors_kernel(int* __restrict__ curA) {
    int i = blockIdx.x * blockDim.x + threadIdx.x;
    if (i < NSEG * 64) curA[i] = i * CAPA2;
}

// Per-element LDS atomic rank: 1 LDS roundtrip, independent across elements
// (vs R10's ballot+atomic+shfl = 2 roundtrips, wave-serialized).
template<int BC>
__device__ __forceinline__ void rank_and_stage(bool ok, int kb, int payload,
                                               int* __restrict__ cnt,
                                               int* __restrict__ stage,
                                               int* __restrict__ gcur,
                                               int* __restrict__ glist,
                                               int gcur_idx, int glim) {
    if (ok) {
        const int pos = atomicAdd(&cnt[kb], 1);
        if (pos < BC) {
            stage[kb * BC + pos] = payload;
        } else {
            const int gp = atomicAdd(&gcur[gcur_idx], 1);
            if (gp < glim) glist[gp] = payload;
        }
    }
}

template<int BC>
__device__ __forceinline__ void flush_bins(int* __restrict__ cnt,
                                           int* __restrict__ basek,
                                           const int* __restrict__ stage,
                                           int* __restrict__ gcur,
                                           int* __restrict__ glist,
                                           int gidx0, int capPer) {
    const int tid = threadIdx.x;
    if (tid < 64) {
        const int m = min(cnt[tid], BC);
        cnt[tid]   = m;
        basek[tid] = atomicAdd(&gcur[gidx0 + tid], m);
    }
    __syncthreads();
    const int w = tid >> 6, lane = tid & 63;
    #pragma unroll 1
    for (int bi = 0; bi < 16; ++bi) {
        const int kb  = w * 16 + bi;
        const int m   = cnt[kb];
        const int gb  = basek[kb];
        const int lim = (gidx0 + kb + 1) * capPer;
        for (int i = lane; i < m; i += 64)
            if (gb + i < lim) glist[gb + i] = stage[kb * BC + i];
    }
}

// ---------------- pass_a body: split by (seg, bucket>>6) ----------------
// payload {sign:31, low6:24..29, g:0..22}. Tile = 512 d -> one segment,
// except ~16 boundary tiles which take a per-entry direct-global slow path.
__device__ __forceinline__ void pass_a_body(int abid, char* smem,
                                            const int* __restrict__ idx,
                                            const int* __restrict__ sgn,
                                            int* __restrict__ curA,
                                            int* __restrict__ listA) {
    int* stage = (int*)smem;                       // 64*96*4 = 24,576 B
    int* cnt   = (int*)(smem + 64 * BINCAP_A * 4);
    int* basek = cnt + 64;
    const int tid = threadIdx.x;
    if (tid < 64) cnt[tid] = 0;
    __syncthreads();

    const int d_lo = abid * 512;
    const int seg  = d_lo / SEG_D;
    const bool boundary = ((d_lo + 511) / SEG_D) != seg;
    const int v0 = abid * (TILE / 4);

    #pragma unroll 1
    for (int k = 0; k < TILE / 1024; ++k) {
        const int vi = v0 + k * 256 + tid;
        const bool okv = vi < NE / 4;
        int4 i4 = {0,0,0,0}, s4 = {0,0,0,0};
        if (okv) { i4 = ((const int4*)idx)[vi]; s4 = ((const int4*)sgn)[vi]; }
        const int g0 = vi * 4;
        #pragma unroll
        for (int m = 0; m < 4; ++m) {
            const int bucket = (m == 0) ? i4.x : (m == 1) ? i4.y : (m == 2) ? i4.z : i4.w;
            const int sg     = (m == 0) ? s4.x : (m == 1) ? s4.y : (m == 2) ? s4.z : s4.w;
            const int kb = okv ? (bucket >> 6) : 0;
            const int payload = (g0 + m) | ((bucket & 63) << 24)
                              | (int)((unsigned)sg & 0x80000000u);
            if (!boundary) {
                rank_and_stage<BINCAP_A>(okv, kb, payload, cnt, stage, curA, listA,
                                         seg * 64 + kb, (seg * 64 + kb + 1) * CAPA2);
            } else if (okv) {                     // rare: per-entry direct
                const int segE = ((g0 + m) >> 3) / SEG_D;
                const int bin  = segE * 64 + kb;
                const int gp = atomicAdd(&curA[bin], 1);
                if (gp < (bin + 1) * CAPA2) listA[gp] = payload;
            }
        }
    }
    __syncthreads();
    flush_bins<BINCAP_A>(cnt, basek, stage, curA, listA, seg * 64, CAPA2);
}

// ---------------- transpose body: x[32][1e6] -> x_T[1e6][32] fp16 ----------------
__device__ __forceinline__ void transpose_body(int tbid, char* smem,
                                               const float* __restrict__ x,
                                               unsigned short* __restrict__ xT) {
    unsigned short (*tile)[260] = (unsigned short(*)[260])smem;  // 16,640 B
    const int tid = threadIdx.x;
    const int d0  = tbid * 256;
    const int row = tid >> 3;
    const int c8  = tid & 7;

    if (d0 + 256 <= D_TOTAL) {
        #pragma unroll
        for (int k = 0; k < 8; ++k) {
            const int c = (c8 + 8 * k) * 4;
            const float4 v = *(const float4*)(x + (size_t)row * D_TOTAL + d0 + c);
            unsigned short h[4];
            h[0] = __half_as_ushort(__float2half(v.x));
            h[1] = __half_as_ushort(__float2half(v.y));
            h[2] = __half_as_ushort(__float2half(v.z));
            h[3] = __half_as_ushort(__float2half(v.w));
            *(uint2*)&tile[row][c] = *(const uint2*)h;
        }
    } else {
        for (int k = 0; k < 8; ++k) {
            const int c = (c8 + 8 * k) * 4;
            for (int m = 0; m < 4; ++m) {
                const int d = d0 + c + m;
                tile[row][c + m] = __half_as_ushort(
                    __float2half((d < D_TOTAL) ? x[(size_t)row * D_TOTAL + d] : 0.f));
            }
        }
    }
    __syncthreads();

    const int part = tid & 3;
    #pragma unroll
    for (int k = 0; k < 4; ++k) {
        const int dl = k * 64 + (tid >> 2);
        if (d0 + dl < D_TOTAL) {
            unsigned short h[8];
            #pragma unroll
            for (int i = 0; i < 8; ++i)
                h[i] = tile[part * 8 + i][dl];
            *(uint4*)(xT + ((size_t)(d0 + dl)) * 32 + part * 8) = *(const uint4*)h;
        }
    }
}

// ---------------- fused pass_a + transpose ----------------
__global__ __launch_bounds__(256, 6)
void pass_a_transpose_kernel(const int* __restrict__ idx, const int* __restrict__ sgn,
                             int* __restrict__ curA, int* __restrict__ listA,
                             const float* __restrict__ x, unsigned short* __restrict__ xT) {
    __shared__ char smem[SMEM_FUSED];
    const int id = blockIdx.x;
    if ((id % 3 == 0) && (id / 3 < NBLK_A)) {
        pass_a_body(id / 3, smem, idx, sgn, curA, listA);
    } else {
        const int tbid = id - id / 3 - ((id % 3) ? 1 : 0);
        if (tbid < NBLK_T) transpose_body(tbid, smem, x, xT);
    }
}

// ---------------- fused pass_b + gather ----------------
// Block = one (seg, kbA, half): stage ~3.9K listA entries by bucket&63 into
// LDS (cap CAPH), then 4 waves x 16 buckets gather from LDS against the
// L2-resident xT segment. Bin overflow (rare, +4.5sig) handled EXACTLY via
// scaled atomics into pre-zeroed out. XCD affinity: gid&7 -> seg group so
// each XCD works one 4MB xT segment at a time.
__global__ __launch_bounds__(256, 6)
void gather_part_kernel(const int* __restrict__ curA, const int* __restrict__ listA,
                        const unsigned short* __restrict__ xT,
                        float* __restrict__ partial, float* __restrict__ out) {
    __shared__ int stage[64 * CAPH];               // 24,576 B
    __shared__ int cnt[64];
    const int tid = threadIdx.x;
    const int gid = blockIdx.x;                    // [0, 2048)
    const int seg  = (gid & 7) + 8 * (gid >> 10);
    const int rest = (gid >> 3) & 127;
    const int kbA  = rest >> 1;
    const int half = rest & 1;
    const int part = seg * 64 + kbA;

    if (tid < 64) cnt[tid] = 0;
    __syncthreads();

    const int pstart = part * CAPA2;
    const int pcount = min(curA[part] - pstart, CAPA2);
    const int hn = (pcount + 1) >> 1;
    const int t0 = half * hn;
    const int t1 = min(t0 + hn, pcount);

    for (int i = t0 + tid; i < t1; i += 256) {
        const int e  = listA[pstart + i];
        const int kb = (e >> 24) & 63;
        const int pos = atomicAdd(&cnt[kb], 1);
        if (pos < CAPH) {
            stage[kb * CAPH + pos] = e;
        } else {
            // exact overflow path: gather this entry straight into out
            int d = (e & 0x7FFFFF) >> 3;
            d = min(d, D_TOTAL - 1);
            const float s = (e < 0) ? -SCALE : SCALE;
            const int p = kbA * 64 + kb;
            for (int b = 0; b < 32; ++b) {
                const float v = __half2float(*(const __half*)(xT + (size_t)d * 32 + b));
                unsafeAtomicAdd(out + (size_t)b * PROJ + p, s * v);
            }
        }
    }
    __syncthreads();

    const int w    = tid >> 6;
    const int lane = tid & 63;
    const int slot = lane >> 2;                    // 16 entry slots
    const int bq   = lane & 3;                     // batch octet
    #pragma unroll 1
    for (int bi = 0; bi < 16; ++bi) {
        const int kb = w * 16 + bi;
        const int n  = min(cnt[kb], CAPH);
        float a0=0.f,a1=0.f,a2=0.f,a3=0.f,a4=0.f,a5=0.f,a6=0.f,a7=0.f;
        #pragma unroll 2
        for (int base = 0; base < n; base += 16) {
            const int  e  = base + slot;
            const bool ok = e < n;
            const int  pl = stage[kb * CAPH + (ok ? e : 0)];
            int d = (pl & 0x7FFFFF) >> 3;
            d = min(d, D_TOTAL - 1);               // clamp vs garbage when n==0
            const float s = ok ? ((pl < 0) ? -1.f : 1.f) : 0.f;
            const uint4 hv = *(const uint4*)(xT + (size_t)d * 32 + bq * 8);
            float2 f;
            f = __half22float2(*(const __half2*)&hv.x); a0 = fmaf(s, f.x, a0); a1 = fmaf(s, f.y, a1);
            f = __half22float2(*(const __half2*)&hv.y); a2 = fmaf(s, f.x, a2); a3 = fmaf(s, f.y, a3);
            f = __half22float2(*(const __half2*)&hv.z); a4 = fmaf(s, f.x, a4); a5 = fmaf(s, f.y, a5);
            f = __half22float2(*(const __half2*)&hv.w); a6 = fmaf(s, f.x, a6); a7 = fmaf(s, f.y, a7);
        }
        #pragma unroll
        for (int m = 4; m <= 32; m <<= 1) {
            a0 += __shfl_xor(a0, m, 64); a1 += __shfl_xor(a1, m, 64);
            a2 += __shfl_xor(a2, m, 64); a3 += __shfl_xor(a3, m, 64);
            a4 += __shfl_xor(a4, m, 64); a5 += __shfl_xor(a5, m, 64);
            a6 += __shfl_xor(a6, m, 64); a7 += __shfl_xor(a7, m, 64);
        }
        if (lane < 4) {
            float v[8] = {a0,a1,a2,a3,a4,a5,a6,a7};
            const size_t slice = (size_t)(seg * 2 + half);
            float* dst = partial + (slice * PROJ + (size_t)(kbA * 64 + kb)) * 32 + lane * 8;
            #pragma unroll
            for (int i = 0; i < 8; ++i) dst[i] = v[i];
        }
    }
}

// ---------------- K6: reduce partials (+overflow already in out) ----------------
__global__ __launch_bounds__(256)
void reduce_kernel(const float* __restrict__ partial, float* __restrict__ out) {
    const int gtid = blockIdx.x * 256 + threadIdx.x;   // [0, 131072)
    const int p = gtid & (PROJ - 1);
    const int b = gtid >> 12;
    float s = 0.f;
    #pragma unroll
    for (int sg = 0; sg < NSLICE; ++sg)
        s += partial[((size_t)(sg * PROJ + p)) * 32 + b];
    const size_t o = (size_t)b * PROJ + p;
    out[o] = out[o] + s * SCALE;                   // out holds exact-overflow adds
}

// ---------------- fallback (R1 kernel) if ws too small ----------------
#define BG 8
#define NCHUNK 64
#define BLOCK 1024
__global__ __launch_bounds__(BLOCK, 4)
void sjlt_scatter_fallback(const float* __restrict__ x,
                           const int* __restrict__ idx,
                           const int* __restrict__ sgn,
                           float* __restrict__ out) {
    __shared__ float acc[BG * PROJ];
    const int tid = threadIdx.x;
    #pragma unroll
    for (int i = 0; i < (BG * PROJ) / BLOCK; ++i) acc[i * BLOCK + tid] = 0.0f;
    __syncthreads();
    const int chunk = D_TOTAL / NCHUNK;
    const int d0 = blockIdx.x * chunk;
    const int d1 = d0 + chunk;
    const int bg = blockIdx.y * BG;
    for (int d = d0 + tid; d < d1; d += BLOCK) {
        const int4 i0 = *(const int4*)(idx + (size_t)d * C_SK);
        const int4 i1 = *(const int4*)(idx + (size_t)d * C_SK + 4);
        const int4 s0 = *(const int4*)(sgn + (size_t)d * C_SK);
        const int4 s1 = *(const int4*)(sgn + (size_t)d * C_SK + 4);
        #pragma unroll
        for (int b = 0; b < BG; ++b) {
            const float xv = __builtin_nontemporal_load(x + (size_t)(bg + b) * D_TOTAL + d);
            const unsigned xb = __float_as_uint(xv);
            float* accb = acc + b * PROJ;
            atomicAdd(accb + i0.x, __uint_as_float(xb ^ ((unsigned)s0.x & 0x80000000u)));
            atomicAdd(accb + i0.y, __uint_as_float(xb ^ ((unsigned)s0.y & 0x80000000u)));
            atomicAdd(accb + i0.z, __uint_as_float(xb ^ ((unsigned)s0.z & 0x80000000u)));
            atomicAdd(accb + i0.w, __uint_as_float(xb ^ ((unsigned)s0.w & 0x80000000u)));
            atomicAdd(accb + i1.x, __uint_as_float(xb ^ ((unsigned)s1.x & 0x80000000u)));
            atomicAdd(accb + i1.y, __uint_as_float(xb ^ ((unsigned)s1.y & 0x80000000u)));
            atomicAdd(accb + i1.z, __uint_as_float(xb ^ ((unsigned)s1.z & 0x80000000u)));
            atomicAdd(accb + i1.w, __uint_as_float(xb ^ ((unsigned)s1.w & 0x80000000u)));
        }
    }
    __syncthreads();
    #pragma unroll
    for (int i = 0; i < (BG * PROJ) / BLOCK; ++i) {
        const int lin = i * BLOCK + tid;
        const int b = lin >> 12;
        const int pp = lin & (PROJ - 1);
        unsafeAtomicAdd(out + (size_t)(bg + b) * PROJ + pp, acc[lin] * SCALE);
    }
}

extern "C" void kernel_launch(void* const* d_in, const int* in_sizes, int n_in,
                              void* d_out, int out_size, void* d_ws, size_t ws_size,
                              hipStream_t stream) {
    const float* x   = (const float*)d_in[0];
    const int*   idx = (const int*)d_in[1];
    const int*   sgn = (const int*)d_in[2];
    float*       out = (float*)d_out;

    if (ws_size < WS_NEED) {
        (void)hipMemsetAsync(out, 0, (size_t)out_size * sizeof(float), stream);
        dim3 grid(NCHUNK, 32 / BG);
        sjlt_scatter_fallback<<<grid, BLOCK, 0, stream>>>(x, idx, sgn, out);
        return;
    }

    char* ws = (char*)d_ws;
    int*            curA    = (int*)(ws + CURA_OFF);
    unsigned short* xT      = (unsigned short*)(ws + XT_OFF);
    int*            listA   = (int*)(ws + LISTA_OFF);
    float*          partial = (float*)(ws + PART_OFF);

    (void)hipMemsetAsync(out, 0, (size_t)out_size * sizeof(float), stream);
    init_cursors_kernel<<<4, 256, 0, stream>>>(curA);
    pass_a_transpose_kernel<<<NBLK_A + NBLK_T, 256, 0, stream>>>(
        idx, sgn, curA, listA, x, xT);
    gather_part_kernel<<<2048, 256, 0, stream>>>(curA, listA, xT, partial, out);
    reduce_kernel<<<(32 * PROJ) / 256, 256, 0, stream>>>(partial, out);
}

// Round 2
// 367.266 us; speedup vs baseline: 1.0085x; 1.0085x over previous
//
#include <hip/hip_runtime.h>
#include <hip/hip_fp16.h>

// SJLT projection: out[b, idx[d,j]] += x[b,d]*sgn[d,j]; out *= 1/sqrt(8)
// B=32, D=1e6, P=4096, c=8.
//
// R11 post-mortem: VALU 21->8% (rank via LDS atomic) but dur flat 103->101us
// -> fused kernel is nothing-bound per counters (HBM 24%, VALU 8%, occ 51%).
// Blended counters prevent attribution. R12: (a) UN-FUSE pass_a / transpose
// for per-body counters; (b) transpose rewritten as register 4dx8b micro-
// transpose: vector LDS both sides (ds_write_b64 / ds_read_b64), XOR-swizzled
// 72B rows (enumerated conflict-free: 32 banks x 4 lanes), 18.4KB LDS ->
// 8 blocks/CU. Predict: transpose ~40us, bank-conflicts ~0; pass_a ~45us.

#define D_TOTAL 1000000
#define PROJ    4096
#define C_SK    8
#define NE      (D_TOTAL * C_SK)     // 8,000,000 entries
#define SCALE   0.35355339059327373f

#define NSEG    16
#define SEG_D   62500                // d per segment (= 4 MB of xT)
#define CAPA2   8448                 // per-(seg,kb) cap (mu=7812, +7.2sig)
#define BINCAP_A 96                  // pass_a per-tile per-bin LDS cap (mu=64,+4sig)
#define CAPH    96                   // gather per-(bucket,half) LDS cap (mu=61,+4.5sig; overflow exact)
#define TILE    4096                 // pass_a tile (512 d)
#define NBLK_A  ((NE + TILE - 1) / TILE)          // 1954
#define NBLK_T  ((D_TOTAL + 255) / 256)           // 3907
#define NSLICE  (NSEG * 2)                        // 32 partial slices

// pass_a smem: stage 64*96*4=24576 + cnt/basek 512 = 25088
#define SMEM_A  25088

// ws layout: curA | xT | listA | partial
#define CURA_OFF   0                                   // 1024 ints (16KB pad)
#define XT_OFF     16384
#define XT_SZ      ((size_t)D_TOTAL * 32 * 2)          // 64,000,000
#define LISTA_OFF  (XT_OFF + XT_SZ)                    // 64,016,384
#define LISTA_SZ   ((size_t)NSEG * 64 * CAPA2 * 4)     // 34,603,008
#define PART_OFF   (LISTA_OFF + LISTA_SZ)              // 98,619,392
#define PART_SZ    ((size_t)NSLICE * PROJ * 32 * 4)    // 16,777,216
#define WS_NEED    (PART_OFF + PART_SZ)                // 115,396,608

// ---------------- K0: init cursors ----------------
__global__ void init_cursors_kernel(int* __restrict__ curA) {
    int i = blockIdx.x * blockDim.x + threadIdx.x;
    if (i < NSEG * 64) curA[i] = i * CAPA2;
}

// Per-element LDS atomic rank: 1 LDS roundtrip, independent across elements.
template<int BC>
__device__ __forceinline__ void rank_and_stage(bool ok, int kb, int payload,
                                               int* __restrict__ cnt,
                                               int* __restrict__ stage,
                                               int* __restrict__ gcur,
                                               int* __restrict__ glist,
                                               int gcur_idx, int glim) {
    if (ok) {
        const int pos = atomicAdd(&cnt[kb], 1);
        if (pos < BC) {
            stage[kb * BC + pos] = payload;
        } else {
            const int gp = atomicAdd(&gcur[gcur_idx], 1);
            if (gp < glim) glist[gp] = payload;
        }
    }
}

template<int BC>
__device__ __forceinline__ void flush_bins(int* __restrict__ cnt,
                                           int* __restrict__ basek,
                                           const int* __restrict__ stage,
                                           int* __restrict__ gcur,
                                           int* __restrict__ glist,
                                           int gidx0, int capPer) {
    const int tid = threadIdx.x;
    if (tid < 64) {
        const int m = min(cnt[tid], BC);
        cnt[tid]   = m;
        basek[tid] = atomicAdd(&gcur[gidx0 + tid], m);
    }
    __syncthreads();
    const int w = tid >> 6, lane = tid & 63;
    #pragma unroll 1
    for (int bi = 0; bi < 16; ++bi) {
        const int kb  = w * 16 + bi;
        const int m   = cnt[kb];
        const int gb  = basek[kb];
        const int lim = (gidx0 + kb + 1) * capPer;
        for (int i = lane; i < m; i += 64)
            if (gb + i < lim) glist[gb + i] = stage[kb * BC + i];
    }
}

// ---------------- pass_a: split by (seg, bucket>>6) ----------------
// payload {sign:31, low6:24..29, g:0..22}. Tile = 512 d -> one segment,
// except ~16 boundary tiles which take a per-entry direct-global slow path.
__device__ __forceinline__ void pass_a_body(int abid, char* smem,
                                            const int* __restrict__ idx,
                                            const int* __restrict__ sgn,
                                            int* __restrict__ curA,
                                            int* __restrict__ listA) {
    int* stage = (int*)smem;                       // 64*96*4 = 24,576 B
    int* cnt   = (int*)(smem + 64 * BINCAP_A * 4);
    int* basek = cnt + 64;
    const int tid = threadIdx.x;
    if (tid < 64) cnt[tid] = 0;
    __syncthreads();

    const int d_lo = abid * 512;
    const int seg  = d_lo / SEG_D;
    const bool boundary = ((d_lo + 511) / SEG_D) != seg;
    const int v0 = abid * (TILE / 4);

    #pragma unroll 1
    for (int k = 0; k < TILE / 1024; ++k) {
        const int vi = v0 + k * 256 + tid;
        const bool okv = vi < NE / 4;
        int4 i4 = {0,0,0,0}, s4 = {0,0,0,0};
        if (okv) { i4 = ((const int4*)idx)[vi]; s4 = ((const int4*)sgn)[vi]; }
        const int g0 = vi * 4;
        #pragma unroll
        for (int m = 0; m < 4; ++m) {
            const int bucket = (m == 0) ? i4.x : (m == 1) ? i4.y : (m == 2) ? i4.z : i4.w;
            const int sg     = (m == 0) ? s4.x : (m == 1) ? s4.y : (m == 2) ? s4.z : s4.w;
            const int kb = okv ? (bucket >> 6) : 0;
            const int payload = (g0 + m) | ((bucket & 63) << 24)
                              | (int)((unsigned)sg & 0x80000000u);
            if (!boundary) {
                rank_and_stage<BINCAP_A>(okv, kb, payload, cnt, stage, curA, listA,
                                         seg * 64 + kb, (seg * 64 + kb + 1) * CAPA2);
            } else if (okv) {                     // rare: per-entry direct
                const int segE = ((g0 + m) >> 3) / SEG_D;
                const int bin  = segE * 64 + kb;
                const int gp = atomicAdd(&curA[bin], 1);
                if (gp < (bin + 1) * CAPA2) listA[gp] = payload;
            }
        }
    }
    __syncthreads();
    flush_bins<BINCAP_A>(cnt, basek, stage, curA, listA, seg * 64, CAPA2);
}

__global__ __launch_bounds__(256, 6)
void pass_a_kernel(const int* __restrict__ idx, const int* __restrict__ sgn,
                   int* __restrict__ curA, int* __restrict__ listA) {
    __shared__ char smem[SMEM_A];
    pass_a_body(blockIdx.x, smem, idx, sgn, curA, listA);
}

// ---------------- transpose: x[32][1e6] -> x_T[1e6][32] fp16 ----------------
// Register 4dx8b micro-transpose. Thread (o=tid&3, dq=tid>>2): loads 8 float4
// (rows o*8+j, cols dq*4..+3; 256B segments), packs halves per-d, writes 2x
// ds_write_b64 per d into tile rows of 72B with XOR swizzle
// c8' = (2o+half)^(dq&7). Enumerated bank map: all 32 banks, 4 lanes each ->
// conflict-free. Phase 2: 2x ds_read_b64 per d (same swizzle), uint4 store
// (1KB contiguous per wave instr). LDS 18,432B -> 8 blocks/CU.
__global__ __launch_bounds__(256, 8)
void transpose_kernel(const float* __restrict__ x, unsigned short* __restrict__ xT) {
    __shared__ __align__(16) unsigned short tile[256 * 36];   // 72B rows
    const int tid = threadIdx.x;
    const int d0  = blockIdx.x * 256;
    const int o   = tid & 3;          // b-octet (b = o*8 .. o*8+7)
    const int dq  = tid >> 2;         // d-quad 0..63
    const int dbase = d0 + dq * 4;

    float4 v[8];
    if (dbase + 4 <= D_TOTAL) {
        #pragma unroll
        for (int j = 0; j < 8; ++j)
            v[j] = *(const float4*)(x + (size_t)(o * 8 + j) * D_TOTAL + dbase);
    } else {
        #pragma unroll
        for (int j = 0; j < 8; ++j) {
            v[j].x = v[j].y = v[j].z = v[j].w = 0.f;
            const float* row = x + (size_t)(o * 8 + j) * D_TOTAL;
            if (dbase + 0 < D_TOTAL) v[j].x = row[dbase + 0];
            if (dbase + 1 < D_TOTAL) v[j].y = row[dbase + 1];
            if (dbase + 2 < D_TOTAL) v[j].z = row[dbase + 2];
            if (dbase + 3 < D_TOTAL) v[j].w = row[dbase + 3];
        }
    }

    const int s = dq & 7;             // row-group swizzle key (row>>2 == dq)
    #pragma unroll
    for (int m = 0; m < 4; ++m) {
        unsigned short h[8];
        #pragma unroll
        for (int j = 0; j < 8; ++j) {
            const float f = (m == 0) ? v[j].x : (m == 1) ? v[j].y
                          : (m == 2) ? v[j].z : v[j].w;
            h[j] = __half_as_ushort(__float2half(f));
        }
        const int row = dq * 4 + m;
        unsigned short* rbase = &tile[row * 36];
        *(uint2*)(rbase + (((2 * o + 0) ^ s) << 2)) = *(const uint2*)&h[0];
        *(uint2*)(rbase + (((2 * o + 1) ^ s) << 2)) = *(const uint2*)&h[4];
    }
    __syncthreads();

    #pragma unroll
    for (int k = 0; k < 4; ++k) {
        const int dl = k * 64 + (tid >> 2);
        if (d0 + dl < D_TOTAL) {
            const int s2 = (dl >> 2) & 7;
            const unsigned short* rbase = &tile[dl * 36];
            const uint2 r0 = *(const uint2*)(rbase + (((2 * o + 0) ^ s2) << 2));
            const uint2 r1 = *(const uint2*)(rbase + (((2 * o + 1) ^ s2) << 2));
            uint4 w; w.x = r0.x; w.y = r0.y; w.z = r1.x; w.w = r1.y;
            *(uint4*)(xT + (size_t)(d0 + dl) * 32 + o * 8) = w;
        }
    }
}

// ---------------- fused pass_b + gather ----------------
// Block = one (seg, kbA, half): stage ~3.9K listA entries by bucket&63 into
// LDS (cap CAPH), then 4 waves x 16 buckets gather from LDS against the
// L2-resident xT segment. Bin overflow (rare, +4.5sig) handled EXACTLY via
// scaled atomics into pre-zeroed out. XCD affinity: gid&7 -> seg group.
__global__ __launch_bounds__(256, 6)
void gather_part_kernel(const int* __restrict__ curA, const int* __restrict__ listA,
                        const unsigned short* __restrict__ xT,
                        float* __restrict__ partial, float* __restrict__ out) {
    __shared__ int stage[64 * CAPH];               // 24,576 B
    __shared__ int cnt[64];
    const int tid = threadIdx.x;
    const int gid = blockIdx.x;                    // [0, 2048)
    const int seg  = (gid & 7) + 8 * (gid >> 10);
    const int rest = (gid >> 3) & 127;
    const int kbA  = rest >> 1;
    const int half = rest & 1;
    const int part = seg * 64 + kbA;

    if (tid < 64) cnt[tid] = 0;
    __syncthreads();

    const int pstart = part * CAPA2;
    const int pcount = min(curA[part] - pstart, CAPA2);
    const int hn = (pcount + 1) >> 1;
    const int t0 = half * hn;
    const int t1 = min(t0 + hn, pcount);

    for (int i = t0 + tid; i < t1; i += 256) {
        const int e  = listA[pstart + i];
        const int kb = (e >> 24) & 63;
        const int pos = atomicAdd(&cnt[kb], 1);
        if (pos < CAPH) {
            stage[kb * CAPH + pos] = e;
        } else {
            // exact overflow path: gather this entry straight into out
            int d = (e & 0x7FFFFF) >> 3;
            d = min(d, D_TOTAL - 1);
            const float sgf = (e < 0) ? -SCALE : SCALE;
            const int p = kbA * 64 + kb;
            for (int b = 0; b < 32; ++b) {
                const float vv = __half2float(*(const __half*)(xT + (size_t)d * 32 + b));
                unsafeAtomicAdd(out + (size_t)b * PROJ + p, sgf * vv);
            }
        }
    }
    __syncthreads();

    const int w    = tid >> 6;
    const int lane = tid & 63;
    const int slot = lane >> 2;                    // 16 entry slots
    const int bq   = lane & 3;                     // batch octet
    #pragma unroll 1
    for (int bi = 0; bi < 16; ++bi) {
        const int kb = w * 16 + bi;
        const int n  = min(cnt[kb], CAPH);
        float a0=0.f,a1=0.f,a2=0.f,a3=0.f,a4=0.f,a5=0.f,a6=0.f,a7=0.f;
        #pragma unroll 2
        for (int base = 0; base < n; base += 16) {
            const int  e  = base + slot;
            const bool ok = e < n;
            const int  pl = stage[kb * CAPH + (ok ? e : 0)];
            int d = (pl & 0x7FFFFF) >> 3;
            d = min(d, D_TOTAL - 1);               // clamp vs garbage when n==0
            const float sg = ok ? ((pl < 0) ? -1.f : 1.f) : 0.f;
            const uint4 hv = *(const uint4*)(xT + (size_t)d * 32 + bq * 8);
            float2 f;
            f = __half22float2(*(const __half2*)&hv.x); a0 = fmaf(sg, f.x, a0); a1 = fmaf(sg, f.y, a1);
            f = __half22float2(*(const __half2*)&hv.y); a2 = fmaf(sg, f.x, a2); a3 = fmaf(sg, f.y, a3);
            f = __half22float2(*(const __half2*)&hv.z); a4 = fmaf(sg, f.x, a4); a5 = fmaf(sg, f.y, a5);
            f = __half22float2(*(const __half2*)&hv.w); a6 = fmaf(sg, f.x, a6); a7 = fmaf(sg, f.y, a7);
        }
        #pragma unroll
        for (int m = 4; m <= 32; m <<= 1) {
            a0 += __shfl_xor(a0, m, 64); a1 += __shfl_xor(a1, m, 64);
            a2 += __shfl_xor(a2, m, 64); a3 += __shfl_xor(a3, m, 64);
            a4 += __shfl_xor(a4, m, 64); a5 += __shfl_xor(a5, m, 64);
            a6 += __shfl_xor(a6, m, 64); a7 += __shfl_xor(a7, m, 64);
        }
        if (lane < 4) {
            float vv[8] = {a0,a1,a2,a3,a4,a5,a6,a7};
            const size_t slice = (size_t)(seg * 2 + half);
            float* dst = partial + (slice * PROJ + (size_t)(kbA * 64 + kb)) * 32 + lane * 8;
            #pragma unroll
            for (int i = 0; i < 8; ++i) dst[i] = vv[i];
        }
    }
}

// ---------------- K6: reduce partials (+overflow already in out) ----------------
__global__ __launch_bounds__(256)
void reduce_kernel(const float* __restrict__ partial, float* __restrict__ out) {
    const int gtid = blockIdx.x * 256 + threadIdx.x;   // [0, 131072)
    const int p = gtid & (PROJ - 1);
    const int b = gtid >> 12;
    float s = 0.f;
    #pragma unroll
    for (int sg = 0; sg < NSLICE; ++sg)
        s += partial[((size_t)(sg * PROJ + p)) * 32 + b];
    const size_t oidx = (size_t)b * PROJ + p;
    out[oidx] = out[oidx] + s * SCALE;             // out holds exact-overflow adds
}

// ---------------- fallback (R1 kernel) if ws too small ----------------
#define BG 8
#define NCHUNK 64
#define BLOCK 1024
__global__ __launch_bounds__(BLOCK, 4)
void sjlt_scatter_fallback(const float* __restrict__ x,
                           const int* __restrict__ idx,
                           const int* __restrict__ sgn,
                           float* __restrict__ out) {
    __shared__ float acc[BG * PROJ];
    const int tid = threadIdx.x;
    #pragma unroll
    for (int i = 0; i < (BG * PROJ) / BLOCK; ++i) acc[i * BLOCK + tid] = 0.0f;
    __syncthreads();
    const int chunk = D_TOTAL / NCHUNK;
    const int d0 = blockIdx.x * chunk;
    const int d1 = d0 + chunk;
    const int bg = blockIdx.y * BG;
    for (int d = d0 + tid; d < d1; d += BLOCK) {
        const int4 i0 = *(const int4*)(idx + (size_t)d * C_SK);
        const int4 i1 = *(const int4*)(idx + (size_t)d * C_SK + 4);
        const int4 s0 = *(const int4*)(sgn + (size_t)d * C_SK);
        const int4 s1 = *(const int4*)(sgn + (size_t)d * C_SK + 4);
        #pragma unroll
        for (int b = 0; b < BG; ++b) {
            const float xv = __builtin_nontemporal_load(x + (size_t)(bg + b) * D_TOTAL + d);
            const unsigned xb = __float_as_uint(xv);
            float* accb = acc + b * PROJ;
            atomicAdd(accb + i0.x, __uint_as_float(xb ^ ((unsigned)s0.x & 0x80000000u)));
            atomicAdd(accb + i0.y, __uint_as_float(xb ^ ((unsigned)s0.y & 0x80000000u)));
            atomicAdd(accb + i0.z, __uint_as_float(xb ^ ((unsigned)s0.z & 0x80000000u)));
            atomicAdd(accb + i0.w, __uint_as_float(xb ^ ((unsigned)s0.w & 0x80000000u)));
            atomicAdd(accb + i1.x, __uint_as_float(xb ^ ((unsigned)s1.x & 0x80000000u)));
            atomicAdd(accb + i1.y, __uint_as_float(xb ^ ((unsigned)s1.y & 0x80000000u)));
            atomicAdd(accb + i1.z, __uint_as_float(xb ^ ((unsigned)s1.z & 0x80000000u)));
            atomicAdd(accb + i1.w, __uint_as_float(xb ^ ((unsigned)s1.w & 0x80000000u)));
        }
    }
    __syncthreads();
    #pragma unroll
    for (int i = 0; i < (BG * PROJ) / BLOCK; ++i) {
        const int lin = i * BLOCK + tid;
        const int b = lin >> 12;
        const int pp = lin & (PROJ - 1);
        unsafeAtomicAdd(out + (size_t)(bg + b) * PROJ + pp, acc[lin] * SCALE);
    }
}

extern "C" void kernel_launch(void* const* d_in, const int* in_sizes, int n_in,
                              void* d_out, int out_size, void* d_ws, size_t ws_size,
                              hipStream_t stream) {
    const float* x   = (const float*)d_in[0];
    const int*   idx = (const int*)d_in[1];
    const int*   sgn = (const int*)d_in[2];
    float*       out = (float*)d_out;

    if (ws_size < WS_NEED) {
        (void)hipMemsetAsync(out, 0, (size_t)out_size * sizeof(float), stream);
        dim3 grid(NCHUNK, 32 / BG);
        sjlt_scatter_fallback<<<grid, BLOCK, 0, stream>>>(x, idx, sgn, out);
        return;
    }

    char* ws = (char*)d_ws;
    int*            curA    = (int*)(ws + CURA_OFF);
    unsigned short* xT      = (unsigned short*)(ws + XT_OFF);
    int*            listA   = (int*)(ws + LISTA_OFF);
    float*          partial = (float*)(ws + PART_OFF);

    (void)hipMemsetAsync(out, 0, (size_t)out_size * sizeof(float), stream);
    init_cursors_kernel<<<4, 256, 0, stream>>>(curA);
    pass_a_kernel<<<NBLK_A, 256, 0, stream>>>(idx, sgn, curA, listA);
    transpose_kernel<<<NBLK_T, 256, 0, stream>>>(x, xT);
    gather_part_kernel<<<2048, 256, 0, stream>>>(curA, listA, xT, partial, out);
    reduce_kernel<<<(32 * PROJ) / 256, 256, 0, stream>>>(partial, out);
}

// Round 5
// 350.316 us; speedup vs baseline: 1.0573x; 1.0484x over previous
//
#include <hip/hip_runtime.h>
#include <hip/hip_fp16.h>

// SJLT projection: out[b, idx[d,j]] += x[b,d]*sgn[d,j]; out *= 1/sqrt(8)
// B=32, D=1e6, P=4096, c=8.
//
// R12 post-mortem: gather = 89us top dispatch, FETCH 192MB vs ~96 ideal ->
// xT segment NOT L2-resident (streams evict it); VALU 39 / HBM 30 / occ 45
// -> latency-bound. R13/R14 compile fixes: __builtin_nontemporal_* needs
// ext_vector_type (not HIP_vector_type); &vec[i] illegal -> copy elem to
// local uint then bit-cast. Plan unchanged: (a) nontemporal on all single-
// touch streams; (b) gather 2-slot MLP + dual accs; (c) coalesced reduce.

#define D_TOTAL 1000000
#define PROJ    4096
#define C_SK    8
#define NE      (D_TOTAL * C_SK)     // 8,000,000 entries
#define SCALE   0.35355339059327373f

#define NSEG    16
#define SEG_D   62500                // d per segment (= 4 MB of xT)
#define CAPA2   8448                 // per-(seg,kb) cap (mu=7812, +7.2sig)
#define BINCAP_A 96                  // pass_a per-tile per-bin LDS cap (mu=64,+4sig)
#define CAPH    96                   // gather per-(bucket,half) LDS cap (mu=61,+4.5sig; overflow exact)
#define TILE    4096                 // pass_a tile (512 d)
#define NBLK_A  ((NE + TILE - 1) / TILE)          // 1954
#define NBLK_T  ((D_TOTAL + 255) / 256)           // 3907
#define NSLICE  (NSEG * 2)                        // 32 partial slices

// native clang vector types: __builtin_nontemporal_* accepts these
typedef int          ni4 __attribute__((ext_vector_type(4)));
typedef float        nf4 __attribute__((ext_vector_type(4)));
typedef unsigned int nu4 __attribute__((ext_vector_type(4)));

// unpack one uint (2 packed halves) -> float2; avoids &vec[i]
__device__ __forceinline__ float2 h2f2(unsigned int u) {
    union { unsigned int u; __half2 h; } cv; cv.u = u;
    return __half22float2(cv.h);
}

// pass_a smem: stage 64*96*4=24576 + cnt/basek 512 = 25088
#define SMEM_A  25088

// ws layout: curA | xT | listA | partial
#define CURA_OFF   0                                   // 1024 ints (16KB pad)
#define XT_OFF     16384
#define XT_SZ      ((size_t)D_TOTAL * 32 * 2)          // 64,000,000
#define LISTA_OFF  (XT_OFF + XT_SZ)                    // 64,016,384
#define LISTA_SZ   ((size_t)NSEG * 64 * CAPA2 * 4)     // 34,603,008
#define PART_OFF   (LISTA_OFF + LISTA_SZ)              // 98,619,392
#define PART_SZ    ((size_t)NSLICE * PROJ * 32 * 4)    // 16,777,216
#define WS_NEED    (PART_OFF + PART_SZ)                // 115,396,608

// ---------------- K0: init cursors ----------------
__global__ void init_cursors_kernel(int* __restrict__ curA) {
    int i = blockIdx.x * blockDim.x + threadIdx.x;
    if (i < NSEG * 64) curA[i] = i * CAPA2;
}

// Per-element LDS atomic rank: 1 LDS roundtrip, independent across elements.
template<int BC>
__device__ __forceinline__ void rank_and_stage(bool ok, int kb, int payload,
                                               int* __restrict__ cnt,
                                               int* __restrict__ stage,
                                               int* __restrict__ gcur,
                                               int* __restrict__ glist,
                                               int gcur_idx, int glim) {
    if (ok) {
        const int pos = atomicAdd(&cnt[kb], 1);
        if (pos < BC) {
            stage[kb * BC + pos] = payload;
        } else {
            const int gp = atomicAdd(&gcur[gcur_idx], 1);
            if (gp < glim) glist[gp] = payload;
        }
    }
}

template<int BC>
__device__ __forceinline__ void flush_bins(int* __restrict__ cnt,
                                           int* __restrict__ basek,
                                           const int* __restrict__ stage,
                                           int* __restrict__ gcur,
                                           int* __restrict__ glist,
                                           int gidx0, int capPer) {
    const int tid = threadIdx.x;
    if (tid < 64) {
        const int m = min(cnt[tid], BC);
        cnt[tid]   = m;
        basek[tid] = atomicAdd(&gcur[gidx0 + tid], m);
    }
    __syncthreads();
    const int w = tid >> 6, lane = tid & 63;
    #pragma unroll 1
    for (int bi = 0; bi < 16; ++bi) {
        const int kb  = w * 16 + bi;
        const int m   = cnt[kb];
        const int gb  = basek[kb];
        const int lim = (gidx0 + kb + 1) * capPer;
        for (int i = lane; i < m; i += 64)
            if (gb + i < lim)
                __builtin_nontemporal_store(stage[kb * BC + i], &glist[gb + i]);
    }
}

// ---------------- pass_a: split by (seg, bucket>>6) ----------------
// payload {sign:31, low6:24..29, g:0..22}. Tile = 512 d -> one segment,
// except ~16 boundary tiles which take a per-entry direct-global slow path.
__device__ __forceinline__ void pass_a_body(int abid, char* smem,
                                            const int* __restrict__ idx,
                                            const int* __restrict__ sgn,
                                            int* __restrict__ curA,
                                            int* __restrict__ listA) {
    int* stage = (int*)smem;                       // 64*96*4 = 24,576 B
    int* cnt   = (int*)(smem + 64 * BINCAP_A * 4);
    int* basek = cnt + 64;
    const int tid = threadIdx.x;
    if (tid < 64) cnt[tid] = 0;
    __syncthreads();

    const int d_lo = abid * 512;
    const int seg  = d_lo / SEG_D;
    const bool boundary = ((d_lo + 511) / SEG_D) != seg;
    const int v0 = abid * (TILE / 4);

    #pragma unroll 1
    for (int k = 0; k < TILE / 1024; ++k) {
        const int vi = v0 + k * 256 + tid;
        const bool okv = vi < NE / 4;
        ni4 i4 = {0,0,0,0}, s4 = {0,0,0,0};
        if (okv) {
            i4 = __builtin_nontemporal_load(&((const ni4*)idx)[vi]);
            s4 = __builtin_nontemporal_load(&((const ni4*)sgn)[vi]);
        }
        const int g0 = vi * 4;
        #pragma unroll
        for (int m = 0; m < 4; ++m) {
            const int bucket = i4[m];
            const int sg     = s4[m];
            const int kb = okv ? (bucket >> 6) : 0;
            const int payload = (g0 + m) | ((bucket & 63) << 24)
                              | (int)((unsigned)sg & 0x80000000u);
            if (!boundary) {
                rank_and_stage<BINCAP_A>(okv, kb, payload, cnt, stage, curA, listA,
                                         seg * 64 + kb, (seg * 64 + kb + 1) * CAPA2);
            } else if (okv) {                     // rare: per-entry direct
                const int segE = ((g0 + m) >> 3) / SEG_D;
                const int bin  = segE * 64 + kb;
                const int gp = atomicAdd(&curA[bin], 1);
                if (gp < (bin + 1) * CAPA2) listA[gp] = payload;
            }
        }
    }
    __syncthreads();
    flush_bins<BINCAP_A>(cnt, basek, stage, curA, listA, seg * 64, CAPA2);
}

__global__ __launch_bounds__(256, 6)
void pass_a_kernel(const int* __restrict__ idx, const int* __restrict__ sgn,
                   int* __restrict__ curA, int* __restrict__ listA) {
    __shared__ char smem[SMEM_A];
    pass_a_body(blockIdx.x, smem, idx, sgn, curA, listA);
}

// ---------------- transpose: x[32][1e6] -> x_T[1e6][32] fp16 ----------------
// Register 4dx8b micro-transpose, XOR-swizzled 72B LDS rows (conflict-free),
// 18.4KB LDS -> 8 blocks/CU. x loads + xT stores nontemporal (single touch).
__global__ __launch_bounds__(256, 8)
void transpose_kernel(const float* __restrict__ x, unsigned short* __restrict__ xT) {
    __shared__ __align__(16) unsigned short tile[256 * 36];   // 72B rows
    const int tid = threadIdx.x;
    const int d0  = blockIdx.x * 256;
    const int o   = tid & 3;          // b-octet (b = o*8 .. o*8+7)
    const int dq  = tid >> 2;         // d-quad 0..63
    const int dbase = d0 + dq * 4;

    nf4 v[8];
    if (dbase + 4 <= D_TOTAL) {
        #pragma unroll
        for (int j = 0; j < 8; ++j)
            v[j] = __builtin_nontemporal_load(
                (const nf4*)(x + (size_t)(o * 8 + j) * D_TOTAL + dbase));
    } else {
        #pragma unroll
        for (int j = 0; j < 8; ++j) {
            v[j] = (nf4){0.f, 0.f, 0.f, 0.f};
            const float* row = x + (size_t)(o * 8 + j) * D_TOTAL;
            if (dbase + 0 < D_TOTAL) v[j][0] = row[dbase + 0];
            if (dbase + 1 < D_TOTAL) v[j][1] = row[dbase + 1];
            if (dbase + 2 < D_TOTAL) v[j][2] = row[dbase + 2];
            if (dbase + 3 < D_TOTAL) v[j][3] = row[dbase + 3];
        }
    }

    const int s = dq & 7;             // row-group swizzle key (row>>2 == dq)
    #pragma unroll
    for (int m = 0; m < 4; ++m) {
        unsigned short h[8];
        #pragma unroll
        for (int j = 0; j < 8; ++j)
            h[j] = __half_as_ushort(__float2half(v[j][m]));
        const int row = dq * 4 + m;
        unsigned short* rbase = &tile[row * 36];
        *(uint2*)(rbase + (((2 * o + 0) ^ s) << 2)) = *(const uint2*)&h[0];
        *(uint2*)(rbase + (((2 * o + 1) ^ s) << 2)) = *(const uint2*)&h[4];
    }
    __syncthreads();

    #pragma unroll
    for (int k = 0; k < 4; ++k) {
        const int dl = k * 64 + (tid >> 2);
        if (d0 + dl < D_TOTAL) {
            const int s2 = (dl >> 2) & 7;
            const unsigned short* rbase = &tile[dl * 36];
            const uint2 r0 = *(const uint2*)(rbase + (((2 * o + 0) ^ s2) << 2));
            const uint2 r1 = *(const uint2*)(rbase + (((2 * o + 1) ^ s2) << 2));
            nu4 w; w[0] = r0.x; w[1] = r0.y; w[2] = r1.x; w[3] = r1.y;
            __builtin_nontemporal_store(
                w, (nu4*)(xT + (size_t)(d0 + dl) * 32 + o * 8));
        }
    }
}

// ---------------- fused pass_b + gather ----------------
// Block = one (seg, kbA, half): stage ~3.9K listA entries by bucket&63 into
// LDS (cap CAPH), then 4 waves x 16 buckets gather from LDS against the
// L2-resident xT segment. Streams (listA read, partial write) nontemporal so
// they don't evict xT from L2. Inner loop: 2 entry-slots per lane + dual
// accumulators -> 4 independent 16B loads in flight per lane.
__global__ __launch_bounds__(256, 6)
void gather_part_kernel(const int* __restrict__ curA, const int* __restrict__ listA,
                        const unsigned short* __restrict__ xT,
                        float* __restrict__ partial, float* __restrict__ out) {
    __shared__ int stage[64 * CAPH];               // 24,576 B
    __shared__ int cnt[64];
    const int tid = threadIdx.x;
    const int gid = blockIdx.x;                    // [0, 2048)
    const int seg  = (gid & 7) + 8 * (gid >> 10);
    const int rest = (gid >> 3) & 127;
    const int kbA  = rest >> 1;
    const int half = rest & 1;
    const int part = seg * 64 + kbA;

    if (tid < 64) cnt[tid] = 0;
    __syncthreads();

    const int pstart = part * CAPA2;
    const int pcount = min(curA[part] - pstart, CAPA2);
    const int hn = (pcount + 1) >> 1;
    const int t0 = half * hn;
    const int t1 = min(t0 + hn, pcount);

    for (int i = t0 + tid; i < t1; i += 256) {
        const int e  = __builtin_nontemporal_load(&listA[pstart + i]);
        const int kb = (e >> 24) & 63;
        const int pos = atomicAdd(&cnt[kb], 1);
        if (pos < CAPH) {
            stage[kb * CAPH + pos] = e;
        } else {
            // exact overflow path: gather this entry straight into out
            int d = (e & 0x7FFFFF) >> 3;
            d = min(d, D_TOTAL - 1);
            const float sgf = (e < 0) ? -SCALE : SCALE;
            const int p = kbA * 64 + kb;
            for (int b = 0; b < 32; ++b) {
                const float vv = __half2float(*(const __half*)(xT + (size_t)d * 32 + b));
                unsafeAtomicAdd(out + (size_t)b * PROJ + p, sgf * vv);
            }
        }
    }
    __syncthreads();

    const int w    = tid >> 6;
    const int lane = tid & 63;
    const int slot = lane >> 2;                    // 16 entry slots
    const int bq   = lane & 3;                     // batch octet
    #pragma unroll 1
    for (int bi = 0; bi < 16; ++bi) {
        const int kb = w * 16 + bi;
        const int n  = min(cnt[kb], CAPH);
        float a0=0.f,a1=0.f,a2=0.f,a3=0.f,a4=0.f,a5=0.f,a6=0.f,a7=0.f;
        float c0=0.f,c1=0.f,c2=0.f,c3=0.f,c4=0.f,c5=0.f,c6=0.f,c7=0.f;
        #pragma unroll 2
        for (int base = 0; base < n; base += 32) {
            const int  e0  = base + slot;
            const int  e1  = base + 16 + slot;
            const bool ok0 = e0 < n;
            const bool ok1 = e1 < n;
            const int  pl0 = stage[kb * CAPH + (ok0 ? e0 : 0)];
            const int  pl1 = stage[kb * CAPH + (ok1 ? e1 : 0)];
            int d0 = (pl0 & 0x7FFFFF) >> 3;  d0 = min(d0, D_TOTAL - 1);
            int d1 = (pl1 & 0x7FFFFF) >> 3;  d1 = min(d1, D_TOTAL - 1);
            const float s0 = ok0 ? ((pl0 < 0) ? -1.f : 1.f) : 0.f;
            const float s1 = ok1 ? ((pl1 < 0) ? -1.f : 1.f) : 0.f;
            const nu4 hv0 = *(const nu4*)(xT + (size_t)d0 * 32 + bq * 8);
            const nu4 hv1 = *(const nu4*)(xT + (size_t)d1 * 32 + bq * 8);
            float2 f;
            f = h2f2(hv0[0]); a0 = fmaf(s0, f.x, a0); a1 = fmaf(s0, f.y, a1);
            f = h2f2(hv0[1]); a2 = fmaf(s0, f.x, a2); a3 = fmaf(s0, f.y, a3);
            f = h2f2(hv0[2]); a4 = fmaf(s0, f.x, a4); a5 = fmaf(s0, f.y, a5);
            f = h2f2(hv0[3]); a6 = fmaf(s0, f.x, a6); a7 = fmaf(s0, f.y, a7);
            f = h2f2(hv1[0]); c0 = fmaf(s1, f.x, c0); c1 = fmaf(s1, f.y, c1);
            f = h2f2(hv1[1]); c2 = fmaf(s1, f.x, c2); c3 = fmaf(s1, f.y, c3);
            f = h2f2(hv1[2]); c4 = fmaf(s1, f.x, c4); c5 = fmaf(s1, f.y, c5);
            f = h2f2(hv1[3]); c6 = fmaf(s1, f.x, c6); c7 = fmaf(s1, f.y, c7);
        }
        a0 += c0; a1 += c1; a2 += c2; a3 += c3;
        a4 += c4; a5 += c5; a6 += c6; a7 += c7;
        #pragma unroll
        for (int m = 4; m <= 32; m <<= 1) {
            a0 += __shfl_xor(a0, m, 64); a1 += __shfl_xor(a1, m, 64);
            a2 += __shfl_xor(a2, m, 64); a3 += __shfl_xor(a3, m, 64);
            a4 += __shfl_xor(a4, m, 64); a5 += __shfl_xor(a5, m, 64);
            a6 += __shfl_xor(a6, m, 64); a7 += __shfl_xor(a7, m, 64);
        }
        if (lane < 4) {
            const size_t slice = (size_t)(seg * 2 + half);
            float* dst = partial + (slice * PROJ + (size_t)(kbA * 64 + kb)) * 32 + lane * 8;
            nf4 v0 = {a0, a1, a2, a3};
            nf4 v1 = {a4, a5, a6, a7};
            __builtin_nontemporal_store(v0, (nf4*)dst);
            __builtin_nontemporal_store(v1, (nf4*)(dst + 4));
        }
    }
}

// ---------------- K6: reduce partials (+overflow already in out) ----------------
// Coalesced: thread = (p, b-quad); wave reads 1KB contiguous per slice.
__global__ __launch_bounds__(256)
void reduce_kernel(const float* __restrict__ partial, float* __restrict__ out) {
    const int tid = threadIdx.x;
    const int bq  = tid & 7;                       // b-quad 0..7 (4 b each)
    const int pl  = tid >> 3;                      // 32 p per block
    const int p   = blockIdx.x * 32 + pl;
    nf4 s = {0.f, 0.f, 0.f, 0.f};
    #pragma unroll
    for (int sg = 0; sg < NSLICE; ++sg) {
        const nf4 v = __builtin_nontemporal_load(
            (const nf4*)(partial + ((size_t)sg * PROJ + p) * 32 + bq * 4));
        s[0] += v[0]; s[1] += v[1]; s[2] += v[2]; s[3] += v[3];
    }
    #pragma unroll
    for (int i = 0; i < 4; ++i) {
        const int b = bq * 4 + i;
        const size_t o = (size_t)b * PROJ + p;
        out[o] = out[o] + s[i] * SCALE;            // out holds exact-overflow adds
    }
}

// ---------------- fallback (R1 kernel) if ws too small ----------------
#define BG 8
#define NCHUNK 64
#define BLOCK 1024
__global__ __launch_bounds__(BLOCK, 4)
void sjlt_scatter_fallback(const float* __restrict__ x,
                           const int* __restrict__ idx,
                           const int* __restrict__ sgn,
                           float* __restrict__ out) {
    __shared__ float acc[BG * PROJ];
    const int tid = threadIdx.x;
    #pragma unroll
    for (int i = 0; i < (BG * PROJ) / BLOCK; ++i) acc[i * BLOCK + tid] = 0.0f;
    __syncthreads();
    const int chunk = D_TOTAL / NCHUNK;
    const int d0 = blockIdx.x * chunk;
    const int d1 = d0 + chunk;
    const int bg = blockIdx.y * BG;
    for (int d = d0 + tid; d < d1; d += BLOCK) {
        const int4 i0 = *(const int4*)(idx + (size_t)d * C_SK);
        const int4 i1 = *(const int4*)(idx + (size_t)d * C_SK + 4);
        const int4 s0 = *(const int4*)(sgn + (size_t)d * C_SK);
        const int4 s1 = *(const int4*)(sgn + (size_t)d * C_SK + 4);
        #pragma unroll
        for (int b = 0; b < BG; ++b) {
            const float xv = __builtin_nontemporal_load(x + (size_t)(bg + b) * D_TOTAL + d);
            const unsigned xb = __float_as_uint(xv);
            float* accb = acc + b * PROJ;
            atomicAdd(accb + i0.x, __uint_as_float(xb ^ ((unsigned)s0.x & 0x80000000u)));
            atomicAdd(accb + i0.y, __uint_as_float(xb ^ ((unsigned)s0.y & 0x80000000u)));
            atomicAdd(accb + i0.z, __uint_as_float(xb ^ ((unsigned)s0.z & 0x80000000u)));
            atomicAdd(accb + i0.w, __uint_as_float(xb ^ ((unsigned)s0.w & 0x80000000u)));
            atomicAdd(accb + i1.x, __uint_as_float(xb ^ ((unsigned)s1.x & 0x80000000u)));
            atomicAdd(accb + i1.y, __uint_as_float(xb ^ ((unsigned)s1.y & 0x80000000u)));
            atomicAdd(accb + i1.z, __uint_as_float(xb ^ ((unsigned)s1.z & 0x80000000u)));
            atomicAdd(accb + i1.w, __uint_as_float(xb ^ ((unsigned)s1.w & 0x80000000u)));
        }
    }
    __syncthreads();
    #pragma unroll
    for (int i = 0; i < (BG * PROJ) / BLOCK; ++i) {
        const int lin = i * BLOCK + tid;
        const int b = lin >> 12;
        const int pp = lin & (PROJ - 1);
        unsafeAtomicAdd(out + (size_t)(bg + b) * PROJ + pp, acc[lin] * SCALE);
    }
}

extern "C" void kernel_launch(void* const* d_in, const int* in_sizes, int n_in,
                              void* d_out, int out_size, void* d_ws, size_t ws_size,
                              hipStream_t stream) {
    const float* x   = (const float*)d_in[0];
    const int*   idx = (const int*)d_in[1];
    const int*   sgn = (const int*)d_in[2];
    float*       out = (float*)d_out;

    if (ws_size < WS_NEED) {
        (void)hipMemsetAsync(out, 0, (size_t)out_size * sizeof(float), stream);
        dim3 grid(NCHUNK, 32 / BG);
        sjlt_scatter_fallback<<<grid, BLOCK, 0, stream>>>(x, idx, sgn, out);
        return;
    }

    char* ws = (char*)d_ws;
    int*            curA    = (int*)(ws + CURA_OFF);
    unsigned short* xT      = (unsigned short*)(ws + XT_OFF);
    int*            listA   = (int*)(ws + LISTA_OFF);
    float*          partial = (float*)(ws + PART_OFF);

    (void)hipMemsetAsync(out, 0, (size_t)out_size * sizeof(float), stream);
    init_cursors_kernel<<<4, 256, 0, stream>>>(curA);
    pass_a_kernel<<<NBLK_A, 256, 0, stream>>>(idx, sgn, curA, listA);
    transpose_kernel<<<NBLK_T, 256, 0, stream>>>(x, xT);
    gather_part_kernel<<<2048, 256, 0, stream>>>(curA, listA, xT, partial, out);
    reduce_kernel<<<PROJ / 32, 256, 0, stream>>>(partial, out);
}